// Round 6
// baseline (3690.871 us; speedup 1.0000x reference)
//
#include <hip/hip_runtime.h>
#include <hip/hip_bf16.h>

// Elman RNN, round 10: fully fused single kernel.
// r9 post-mortem: scan pinned at ~1110 us; the non-scan gap was ~240 us across
// FOUR different phase-1 implementations (strided writes, tile writes, 1024 vs
// 2048 blocks) while phase-1's compute floor is ~45 us -> the gap is fixed
// overhead (2nd launch + xin HBM round-trip + latency-bound mini-GEMM), not
// phase-1 internals. Fusing eliminates it by construction:
//  - per step, each wave adds 8 input MFMAs (W_in x-frags, K=128) that are
//    register-only and independent of the h-chain -> they fill the matrix-pipe
//    idle during barrier-wait/ds_read latency (active-CU MfmaUtil was only 39%).
//  - x(t) loaded raw fp32 two steps ahead (in flight across the lgkm-only
//    barrier), converted to bf16 frags the next step -> HBM latency hidden,
//    no LDS staging for x, DS traffic unchanged.
//  - accN for step t+1 is built during step t (bias + input MFMAs), swapped in
//    via 2x-unrolled loop naming.
// Scan core unchanged from r9 (passed): 8 waves x 2 m-tiles, conflict-free
// interleaved h C-tile LDS layout, lgkm-only barrier, sigmoid via exp2/rcp with
// log2e folded into all weights/bias.

#define BATCH 128
#define SEQ   2048
#define NIN   128
#define NH    256
#define NOUT  128

#define BTILE 16
#define NBLK  (BATCH / BTILE)      // 8
#define LOG2E 1.4426950408889634f

typedef __attribute__((ext_vector_type(8))) short short8;
typedef __attribute__((ext_vector_type(4))) float f32x4;

__device__ __forceinline__ ushort f2bf(float f) {
    union { float f; uint u; } v; v.f = f;
    uint r = v.u + 0x7fffu + ((v.u >> 16) & 1u);   // RNE
    return (ushort)(r >> 16);
}

// packed f32->bf16 RNE via builtin (m240: do not hand-write the asm)
__device__ __forceinline__ uint pk_bf16(float a, float b) {
    float2 p; p.x = a; p.y = b;
    __hip_bfloat162 h = __float22bfloat162_rn(p);
    union { __hip_bfloat162 h; uint u; } v; v.h = h; return v.u;
}

__device__ __forceinline__ short8 load_wfrag_s(const float* __restrict__ W, int ld,
                                               int row, int col, float scale) {
    const float4* p = (const float4*)(W + (size_t)row * ld + col);
    float4 a = p[0], b = p[1];
    union { short8 v; ushort u[8]; } r;
    r.u[0] = f2bf(a.x * scale); r.u[1] = f2bf(a.y * scale);
    r.u[2] = f2bf(a.z * scale); r.u[3] = f2bf(a.w * scale);
    r.u[4] = f2bf(b.x * scale); r.u[5] = f2bf(b.y * scale);
    r.u[6] = f2bf(b.z * scale); r.u[7] = f2bf(b.w * scale);
    return r.v;
}

__global__ __launch_bounds__(512, 2)
void elman_fused(const float* __restrict__ x,
                 const float* __restrict__ W_in,
                 const float* __restrict__ b_in,
                 const float* __restrict__ W_rec,
                 const float* __restrict__ W_out,
                 const float* __restrict__ b_out,
                 float* __restrict__ out) {
    const int tid  = threadIdx.x;
    const int lane = tid & 63;
    const int wid  = tid >> 6;          // 0..7 -> m-tiles wid*2, wid*2+1
    const int n15  = lane & 15;
    const int q    = lane >> 4;
    const int bblk = blockIdx.x * BTILE;

    // interleaved C-tile layout: uint2 at [slot*64 + c*4 + q']
    __shared__ __align__(16) uint2 hlds[2][16 * 64];   // 2 x 8 KB

    // weights in registers, log2e folded
    short8 wrec[2][8];   // 64 VGPR
    short8 win[2][4];    // 32 VGPR
    f32x4  bias[2];      // 8 VGPR
    #pragma unroll
    for (int mt = 0; mt < 2; ++mt) {
        const int row = (wid * 2 + mt) * 16 + n15;
        #pragma unroll
        for (int kt = 0; kt < 8; ++kt)
            wrec[mt][kt] = load_wfrag_s(W_rec, NH, row, kt * 32 + q * 8, LOG2E);
        #pragma unroll
        for (int kt = 0; kt < 4; ++kt)
            win[mt][kt] = load_wfrag_s(W_in, NIN, row, kt * 32 + q * 8, LOG2E);
        #pragma unroll
        for (int r = 0; r < 4; ++r)
            bias[mt][r] = LOG2E * b_in[(wid * 2 + mt) * 16 + q * 4 + r];
    }

    // h0 = 0
    for (int i = tid; i < 16 * 64; i += 512) {
        uint2 z; z.x = 0u; z.y = 0u;
        hlds[0][i] = z;
    }

    // ---- x pipeline: raw fp32 loads 2 steps ahead, cvt next step ----
    // lane (n15,q) B-frag kt of x(t): x[bblk+n15][t][kt*32 + q*8 .. +7]
    const float* xrow = x + (size_t)(bblk + n15) * SEQ * NIN + q * 8;

    float4 xr[4][2];     // 32 VGPR raw in-flight buffer
    short8 bx0[4], bx1[4];  // 32 VGPR converted frags

    auto xload = [&](int t) {
        const float* xp = xrow + (size_t)t * NIN;
        #pragma unroll
        for (int kt = 0; kt < 4; ++kt) {
            const float4* p = (const float4*)(xp + kt * 32);
            xr[kt][0] = p[0];
            xr[kt][1] = p[1];
        }
    };
    auto xcvt = [&](short8 (&dst)[4]) {
        #pragma unroll
        for (int kt = 0; kt < 4; ++kt) {
            union { short8 v; uint u[4]; } r;
            r.u[0] = pk_bf16(xr[kt][0].x, xr[kt][0].y);
            r.u[1] = pk_bf16(xr[kt][0].z, xr[kt][0].w);
            r.u[2] = pk_bf16(xr[kt][1].x, xr[kt][1].y);
            r.u[3] = pk_bf16(xr[kt][1].z, xr[kt][1].w);
            dst[kt] = r.v;
        }
    };

    f32x4 accA[2], accB[2];

    // prologue: accA = bias + x(0).W_in^T ; bx1 = x(1) ; xr <- x(2) in flight
    xload(0); xcvt(bx0);
    #pragma unroll
    for (int mt = 0; mt < 2; ++mt) accA[mt] = bias[mt];
    #pragma unroll
    for (int kt = 0; kt < 4; ++kt)
        #pragma unroll
        for (int mt = 0; mt < 2; ++mt)
            accA[mt] = __builtin_amdgcn_mfma_f32_16x16x32_bf16(
                win[mt][kt], bx0[kt], accA[mt], 0, 0, 0);
    xload(1); xcvt(bx1);
    xload(2);                      // stays in flight across the loop entry

    __syncthreads();

    // B-frag read: rows 32kt+8q..+7, col n15 == one aligned b128 at this uint2 idx
    const int rbase = n15 * 4 + 2 * (q & 1);
    const int shalf = q >> 1;
    // write offset for this lane's C output (c*4 + q')
    const int woff  = n15 * 4 + q;

    // step t: consume acc (= bias + x(t).W_in), build accN for t+1 from bxc
    // (= x(t+1)), refill bxf from xr (= x(t+2)), issue loads x(t+3) -> xr.
    auto step = [&](int t, f32x4 (&acc)[2], f32x4 (&accN)[2],
                    short8 (&bxc)[4], short8 (&bxf)[4]) {
        const int cur = t & 1, nxt = cur ^ 1;

        // 1) h_t B-fragments: 8 conflict-free ds_read_b128
        short8 bh[8];
        #pragma unroll
        for (int kt = 0; kt < 8; ++kt)
            bh[kt] = *(const short8*)&hlds[cur][(2 * kt + shalf) * 64 + rbase];

        __builtin_amdgcn_s_setprio(1);
        // 2) input MFMAs for t+1 — register-only, fills pipe during ds latency
        #pragma unroll
        for (int mt = 0; mt < 2; ++mt) accN[mt] = bias[mt];
        #pragma unroll
        for (int kt = 0; kt < 4; ++kt)
            #pragma unroll
            for (int mt = 0; mt < 2; ++mt)
                accN[mt] = __builtin_amdgcn_mfma_f32_16x16x32_bf16(
                    win[mt][kt], bxc[kt], accN[mt], 0, 0, 0);

        // 3) recurrent MFMAs: 2 independent chains x 8 deep
        #pragma unroll
        for (int kt = 0; kt < 8; ++kt)
            #pragma unroll
            for (int mt = 0; mt < 2; ++mt)
                acc[mt] = __builtin_amdgcn_mfma_f32_16x16x32_bf16(
                    wrec[mt][kt], bh[kt], acc[mt], 0, 0, 0);
        __builtin_amdgcn_s_setprio(0);

        // 4) cvt raw x(t+2) -> bxf (waits its vmcnt), then issue x(t+3) loads
        xcvt(bxf);
        {
            const int tf = (t + 3 < SEQ) ? (t + 3) : (SEQ - 1);
            xload(tf);
        }

        // 5) sigmoid(a) = rcp(1 + 2^(-z)), z = log2e*a already in acc; tile write
        #pragma unroll
        for (int mt = 0; mt < 2; ++mt) {
            float h0 = __builtin_amdgcn_rcpf(1.0f + __builtin_amdgcn_exp2f(-acc[mt][0]));
            float h1 = __builtin_amdgcn_rcpf(1.0f + __builtin_amdgcn_exp2f(-acc[mt][1]));
            float h2 = __builtin_amdgcn_rcpf(1.0f + __builtin_amdgcn_exp2f(-acc[mt][2]));
            float h3 = __builtin_amdgcn_rcpf(1.0f + __builtin_amdgcn_exp2f(-acc[mt][3]));
            uint2 w;
            w.x = pk_bf16(h0, h1);
            w.y = pk_bf16(h2, h3);
            hlds[nxt][(wid * 2 + mt) * 64 + woff] = w;
        }

        // lgkm-only barrier: LDS drained, global x loads stay in flight
        asm volatile("s_waitcnt lgkmcnt(0)" ::: "memory");
        __builtin_amdgcn_s_barrier();
    };

    #pragma unroll 1
    for (int t = 0; t < SEQ; t += 2) {
        step(t,     accA, accB, bx1, bx0);   // consume x(t+1), refill bx0 = x(t+2)
        step(t + 1, accB, accA, bx0, bx1);   // consume x(t+2), refill bx1 = x(t+3)
    }

    // ---- output projection from hlds[0] (SEQ even): wave wid owns m-tile wid ----
    short8 wout[8];
    float  bo[4];
    {
        const int row = wid * 16 + n15;
        #pragma unroll
        for (int kt = 0; kt < 8; ++kt)
            wout[kt] = load_wfrag_s(W_out, NH, row, kt * 32 + q * 8, 1.0f);
        #pragma unroll
        for (int r = 0; r < 4; ++r)
            bo[r] = b_out[wid * 16 + q * 4 + r];
    }
    f32x4 oacc;
    oacc[0] = bo[0]; oacc[1] = bo[1]; oacc[2] = bo[2]; oacc[3] = bo[3];
    #pragma unroll
    for (int kt = 0; kt < 8; ++kt) {
        short8 bh = *(const short8*)&hlds[0][(2 * kt + shalf) * 64 + rbase];
        oacc = __builtin_amdgcn_mfma_f32_16x16x32_bf16(wout[kt], bh, oacc, 0, 0, 0);
    }
    #pragma unroll
    for (int r = 0; r < 4; ++r) {
        const int o = wid * 16 + q * 4 + r;
        out[(size_t)(bblk + n15) * NOUT + o] = oacc[r];
    }
}

extern "C" void kernel_launch(void* const* d_in, const int* in_sizes, int n_in,
                              void* d_out, int out_size, void* d_ws, size_t ws_size,
                              hipStream_t stream) {
    const float* x     = (const float*)d_in[0];
    const float* W_in  = (const float*)d_in[1];
    const float* b_in  = (const float*)d_in[2];
    const float* W_rec = (const float*)d_in[3];
    const float* W_out = (const float*)d_in[4];
    const float* b_out = (const float*)d_in[5];
    float* out = (float*)d_out;

    elman_fused<<<NBLK, 512, 0, stream>>>(x, W_in, b_in, W_rec, W_out, b_out, out);
}

// Round 7
// 1437.697 us; speedup vs baseline: 2.5672x; 2.5672x over previous
//
#include <hip/hip_runtime.h>
#include <hip/hip_bf16.h>

// Elman RNN, round 11: single-launch producer/consumer overlap.
// r10 post-mortem: true fusion collapsed (VGPR 128 vs ~230 needed -> spill;
// x-load VMEM work moved onto the 8 scan CUs) -> 3549 us. The gap (242 us) is
// launch+serialization overhead, so overlap instead of fuse:
//  - one kernel, 2056 blocks: blockIdx 0..7 = r9 scan (unchanged, 1109 us);
//    blockIdx 8.. = 2048 producers, each computes xin for one (batch-tile b,
//    8-step chunk c) exactly as r9's xin_gemm, on OTHER CUs, overlapped.
//  - sync: flags[b][c] in d_ws. Producer: syncthreads -> threadfence ->
//    release-store flag (agent scope). Consumer: every 8 steps, thread 0
//    acquire-polls flag[c+1], syncthreads, agent acquire-fence (G16 pattern;
//    xin lines are first-touch on the consumer XCD, fence kills speculation).
//    Producers never wait -> no deadlock. Consumers are blocks 0..7 ->
//    dispatched first.
//  - 96 KB dynamic LDS -> 1 block/CU: producers never co-reside with scan CUs.
//    2048 producers / ~248 CUs ~ 8 rounds ~ 60-90 us << scan; consumption rate
//    4.3 us/chunk -> gates almost never spin.
//  - ws too small for flags -> exact r9 two-kernel fallback.

#define BATCH 128
#define SEQ   2048
#define NIN   128
#define NH    256
#define NOUT  128

#define BTILE 16
#define NBLK  (BATCH / BTILE)      // 8
#define TCHUNK 8
#define NCHUNK (SEQ / TCHUNK)      // 256
#define LOG2E 1.4426950408889634f
#define HPITCH 264                 // (fallback-only)
#define XPITCH 136                 // (fallback-only)

typedef __attribute__((ext_vector_type(8))) short short8;
typedef __attribute__((ext_vector_type(4))) float f32x4;

__device__ __forceinline__ ushort f2bf(float f) {
    union { float f; uint u; } v; v.f = f;
    uint r = v.u + 0x7fffu + ((v.u >> 16) & 1u);   // RNE
    return (ushort)(r >> 16);
}

// packed f32->bf16 RNE via builtin (m240: do not hand-write the asm)
__device__ __forceinline__ uint pk_bf16(float a, float b) {
    float2 p; p.x = a; p.y = b;
    __hip_bfloat162 h = __float22bfloat162_rn(p);
    union { __hip_bfloat162 h; uint u; } v; v.h = h; return v.u;
}

__device__ __forceinline__ short8 load_wfrag_s(const float* __restrict__ W, int ld,
                                               int row, int col, float scale) {
    const float4* p = (const float4*)(W + (size_t)row * ld + col);
    float4 a = p[0], b = p[1];
    union { short8 v; ushort u[8]; } r;
    r.u[0] = f2bf(a.x * scale); r.u[1] = f2bf(a.y * scale);
    r.u[2] = f2bf(a.z * scale); r.u[3] = f2bf(a.w * scale);
    r.u[4] = f2bf(b.x * scale); r.u[5] = f2bf(b.y * scale);
    r.u[6] = f2bf(b.z * scale); r.u[7] = f2bf(b.w * scale);
    return r.v;
}

__device__ __forceinline__ float bfhi2f(uint u) {
    union { uint u; float f; } v; v.u = u & 0xffff0000u; return v.f;
}
__device__ __forceinline__ float bflo2f(uint u) {
    union { uint u; float f; } v; v.u = u << 16; return v.f;
}

// =================== single-launch producer/consumer kernel ===================
__global__ __launch_bounds__(512, 2)
void elman_fused(const float* __restrict__ x,
                 const float* __restrict__ W_in,
                 const float* __restrict__ b_in,
                 const float* __restrict__ W_rec,
                 const float* __restrict__ W_out,
                 const float* __restrict__ b_out,
                 float* __restrict__ out,
                 uint2* __restrict__ xin,
                 uint*  __restrict__ flags) {
    const int tid  = threadIdx.x;
    const int lane = tid & 63;
    const int wid  = tid >> 6;          // 0..7
    const int n15  = lane & 15;
    const int q    = lane >> 4;

    // interleaved C-tile layout: uint2 at [slot*64 + c*4 + q'] (consumer only)
    __shared__ __align__(16) uint2 hlds[2][16 * 64];   // 16 KB static

    if (blockIdx.x >= NBLK) {
        // ------------------------- producer -------------------------
        // pid -> (chunk c, batch-tile b); dispatch order gives ascending c.
        const int pid  = blockIdx.x - NBLK;
        const int c    = pid >> 3;
        const int b    = pid & 7;
        const int bblk = b * BTILE;
        const int t0   = c * TCHUNK;

        short8 win[2][4];
        float  bias[2][4];
        #pragma unroll
        for (int mt = 0; mt < 2; ++mt) {
            const int row = (wid * 2 + mt) * 16 + n15;
            #pragma unroll
            for (int kt = 0; kt < 4; ++kt)
                win[mt][kt] = load_wfrag_s(W_in, NIN, row, kt * 32 + q * 8, LOG2E);
            #pragma unroll
            for (int r = 0; r < 4; ++r)
                bias[mt][r] = LOG2E * b_in[(wid * 2 + mt) * 16 + q * 4 + r];
        }

        const float* xrow = x + ((size_t)(bblk + n15) * SEQ + t0) * NIN + q * 8;

        #pragma unroll 1
        for (int tt = 0; tt < TCHUNK; ++tt) {
            const float* xp = xrow + (size_t)tt * NIN;
            short8 bx[4];
            #pragma unroll
            for (int kt = 0; kt < 4; ++kt) {
                const float4* p = (const float4*)(xp + kt * 32);
                float4 a = p[0], bb = p[1];
                union { short8 v; uint u[4]; } r;
                r.u[0] = pk_bf16(a.x, a.y);
                r.u[1] = pk_bf16(a.z, a.w);
                r.u[2] = pk_bf16(bb.x, bb.y);
                r.u[3] = pk_bf16(bb.z, bb.w);
                bx[kt] = r.v;
            }
            f32x4 acc[2];
            #pragma unroll
            for (int mt = 0; mt < 2; ++mt) {
                acc[mt][0] = bias[mt][0]; acc[mt][1] = bias[mt][1];
                acc[mt][2] = bias[mt][2]; acc[mt][3] = bias[mt][3];
            }
            #pragma unroll
            for (int kt = 0; kt < 4; ++kt)
                #pragma unroll
                for (int mt = 0; mt < 2; ++mt)
                    acc[mt] = __builtin_amdgcn_mfma_f32_16x16x32_bf16(
                        win[mt][kt], bx[kt], acc[mt], 0, 0, 0);

            const uint tb = ((uint)(t0 + tt) * NBLK + (uint)b) * 16u;
            #pragma unroll
            for (int mt = 0; mt < 2; ++mt) {
                uint2 w;
                w.x = pk_bf16(acc[mt][0], acc[mt][1]);
                w.y = pk_bf16(acc[mt][2], acc[mt][3]);
                xin[(size_t)((tb + wid * 2 + mt) * 64u + lane)] = w;
            }
        }

        __syncthreads();                       // all stores issued & counted
        if (tid == 0) {
            __threadfence();                   // agent fence: L2 -> MALL
            __hip_atomic_store(&flags[b * NCHUNK + c], 1u,
                               __ATOMIC_RELEASE, __HIP_MEMORY_SCOPE_AGENT);
        }
        return;
    }

    // ------------------------- consumer: r9 scan + gates -------------------------
    const int  bblk  = blockIdx.x * BTILE;
    const uint fbase = (uint)blockIdx.x * NCHUNK;

    short8 wrec[2][8];
    #pragma unroll
    for (int mt = 0; mt < 2; ++mt) {
        const int row = (wid * 2 + mt) * 16 + n15;
        #pragma unroll
        for (int kt = 0; kt < 8; ++kt)
            wrec[mt][kt] = load_wfrag_s(W_rec, NH, row, kt * 32 + q * 8, LOG2E);
    }

    for (int i = tid; i < 16 * 64; i += 512) {
        uint2 z; z.x = 0u; z.y = 0u;
        hlds[0][i] = z;
    }

    const uint loff = (uint)blockIdx.x * 1024u + (uint)(wid * 2) * 64u + (uint)lane;

    // chunk gate: thread 0 acquire-polls, block barriers, all-thread acquire fence
    auto gate = [&](int cc) {
        if (tid == 0) {
            while (__hip_atomic_load(&flags[fbase + (uint)cc],
                                     __ATOMIC_ACQUIRE, __HIP_MEMORY_SCOPE_AGENT) == 0u)
                __builtin_amdgcn_s_sleep(8);
        }
        __syncthreads();
        __builtin_amdgcn_fence(__ATOMIC_ACQUIRE, "agent");
    };

    gate(0);                                    // chunk 0 ready before t=0,1 loads

    uint2 xa[2], xb[2];
    #pragma unroll
    for (int mt = 0; mt < 2; ++mt) xa[mt] = xin[(size_t)(loff + mt * 64u)];           // t=0
    #pragma unroll
    for (int mt = 0; mt < 2; ++mt) xb[mt] = xin[(size_t)(8192u + loff + mt * 64u)];   // t=1

    __syncthreads();

    const int rbase = n15 * 4 + 2 * (q & 1);
    const int shalf = q >> 1;
    const int woff  = n15 * 4 + q;

    auto step = [&](int t, uint2 (&X)[2]) {
        const int cur = t & 1, nxt = cur ^ 1;

        short8 bh[8];
        #pragma unroll
        for (int kt = 0; kt < 8; ++kt)
            bh[kt] = *(const short8*)&hlds[cur][(2 * kt + shalf) * 64 + rbase];

        f32x4 acc[2];
        #pragma unroll
        for (int mt = 0; mt < 2; ++mt) {
            acc[mt][0] = bflo2f(X[mt].x);
            acc[mt][1] = bfhi2f(X[mt].x);
            acc[mt][2] = bflo2f(X[mt].y);
            acc[mt][3] = bfhi2f(X[mt].y);
        }

        {   // prefetch xin_{t+2}; vmcnt floats across the lgkm-only barrier
            const uint tp = (uint)((t + 2 < SEQ) ? (t + 2) : (SEQ - 1));
            const uint tb = tp * 8192u + loff;
            #pragma unroll
            for (int mt = 0; mt < 2; ++mt) X[mt] = xin[(size_t)(tb + mt * 64u)];
        }

        __builtin_amdgcn_s_setprio(1);
        #pragma unroll
        for (int kt = 0; kt < 8; ++kt)
            #pragma unroll
            for (int mt = 0; mt < 2; ++mt)
                acc[mt] = __builtin_amdgcn_mfma_f32_16x16x32_bf16(
                    wrec[mt][kt], bh[kt], acc[mt], 0, 0, 0);
        __builtin_amdgcn_s_setprio(0);

        #pragma unroll
        for (int mt = 0; mt < 2; ++mt) {
            float h0 = __builtin_amdgcn_rcpf(1.0f + __builtin_amdgcn_exp2f(-acc[mt][0]));
            float h1 = __builtin_amdgcn_rcpf(1.0f + __builtin_amdgcn_exp2f(-acc[mt][1]));
            float h2 = __builtin_amdgcn_rcpf(1.0f + __builtin_amdgcn_exp2f(-acc[mt][2]));
            float h3 = __builtin_amdgcn_rcpf(1.0f + __builtin_amdgcn_exp2f(-acc[mt][3]));
            uint2 w;
            w.x = pk_bf16(h0, h1);
            w.y = pk_bf16(h2, h3);
            hlds[nxt][(wid * 2 + mt) * 64 + woff] = w;
        }

        asm volatile("s_waitcnt lgkmcnt(0)" ::: "memory");
        __builtin_amdgcn_s_barrier();
    };

    #pragma unroll 1
    for (int t = 0; t < SEQ; t += 2) {
        if ((t & 7) == 0) {
            const int cc = (t >> 3) + 1;
            gate(cc < NCHUNK ? cc : NCHUNK - 1);   // covers prefetch into chunk c+1
        }
        step(t, xa);
        step(t + 1, xb);
    }

    // ---- output projection from hlds[0] (SEQ even): wave wid owns m-tile wid ----
    short8 wout[8];
    float  bo[4];
    {
        const int row = wid * 16 + n15;
        #pragma unroll
        for (int kt = 0; kt < 8; ++kt)
            wout[kt] = load_wfrag_s(W_out, NH, row, kt * 32 + q * 8, 1.0f);
        #pragma unroll
        for (int r = 0; r < 4; ++r)
            bo[r] = b_out[wid * 16 + q * 4 + r];
    }
    f32x4 oacc;
    oacc[0] = bo[0]; oacc[1] = bo[1]; oacc[2] = bo[2]; oacc[3] = bo[3];
    #pragma unroll
    for (int kt = 0; kt < 8; ++kt) {
        short8 bh = *(const short8*)&hlds[0][(2 * kt + shalf) * 64 + rbase];
        oacc = __builtin_amdgcn_mfma_f32_16x16x32_bf16(wout[kt], bh, oacc, 0, 0, 0);
    }
    #pragma unroll
    for (int r = 0; r < 4; ++r) {
        const int o = wid * 16 + q * 4 + r;
        out[(size_t)(bblk + n15) * NOUT + o] = oacc[r];
    }
}

// =================== fallback: exact r9 two-kernel path ===================
__global__ __launch_bounds__(256, 2)
void xin_gemm(const float* __restrict__ x,
              const float* __restrict__ W_in,
              const float* __restrict__ b_in,
              uint2* __restrict__ xin) {
    const int tid  = threadIdx.x;
    const int lane = tid & 63;
    const int wid  = tid >> 6;
    const int n15  = lane & 15;
    const int q    = lane >> 4;
    const int bblk = blockIdx.x * BTILE;
    const int t0   = blockIdx.y * TCHUNK;

    short8 win[4][4];
    float  bias[4][4];
    #pragma unroll
    for (int mt = 0; mt < 4; ++mt) {
        const int row = (wid * 4 + mt) * 16 + n15;
        #pragma unroll
        for (int kt = 0; kt < 4; ++kt)
            win[mt][kt] = load_wfrag_s(W_in, NIN, row, kt * 32 + q * 8, LOG2E);
        #pragma unroll
        for (int r = 0; r < 4; ++r)
            bias[mt][r] = LOG2E * b_in[(wid * 4 + mt) * 16 + q * 4 + r];
    }

    const float* xrow = x + ((size_t)(bblk + n15) * SEQ + t0) * NIN + q * 8;

    #pragma unroll 1
    for (int tt = 0; tt < TCHUNK; ++tt) {
        const float* xp = xrow + (size_t)tt * NIN;
        short8 bx[4];
        #pragma unroll
        for (int kt = 0; kt < 4; ++kt) {
            const float4* p = (const float4*)(xp + kt * 32);
            float4 a = p[0], b = p[1];
            union { short8 v; uint u[4]; } r;
            r.u[0] = pk_bf16(a.x, a.y);
            r.u[1] = pk_bf16(a.z, a.w);
            r.u[2] = pk_bf16(b.x, b.y);
            r.u[3] = pk_bf16(b.z, b.w);
            bx[kt] = r.v;
        }
        f32x4 acc[4];
        #pragma unroll
        for (int mt = 0; mt < 4; ++mt) {
            acc[mt][0] = bias[mt][0]; acc[mt][1] = bias[mt][1];
            acc[mt][2] = bias[mt][2]; acc[mt][3] = bias[mt][3];
        }
        #pragma unroll
        for (int kt = 0; kt < 4; ++kt)
            #pragma unroll
            for (int mt = 0; mt < 4; ++mt)
                acc[mt] = __builtin_amdgcn_mfma_f32_16x16x32_bf16(
                    win[mt][kt], bx[kt], acc[mt], 0, 0, 0);

        const uint tb = ((uint)(t0 + tt) * NBLK + blockIdx.x) * 16u;
        #pragma unroll
        for (int mt = 0; mt < 4; ++mt) {
            uint2 w;
            w.x = pk_bf16(acc[mt][0], acc[mt][1]);
            w.y = pk_bf16(acc[mt][2], acc[mt][3]);
            xin[(size_t)((tb + wid * 4 + mt) * 64u + lane)] = w;
        }
    }
}

__global__ __launch_bounds__(512, 2)
void elman_scan(const uint2* __restrict__ xin,
                const float* __restrict__ W_rec,
                const float* __restrict__ W_out,
                const float* __restrict__ b_out,
                float* __restrict__ out) {
    const int tid  = threadIdx.x;
    const int lane = tid & 63;
    const int wid  = tid >> 6;
    const int n15  = lane & 15;
    const int q    = lane >> 4;
    const int bblk = blockIdx.x * BTILE;

    __shared__ __align__(16) uint2 hlds[2][16 * 64];

    short8 wrec[2][8];
    #pragma unroll
    for (int mt = 0; mt < 2; ++mt) {
        const int row = (wid * 2 + mt) * 16 + n15;
        #pragma unroll
        for (int kt = 0; kt < 8; ++kt)
            wrec[mt][kt] = load_wfrag_s(W_rec, NH, row, kt * 32 + q * 8, LOG2E);
    }

    for (int i = tid; i < 16 * 64; i += 512) {
        uint2 z; z.x = 0u; z.y = 0u;
        hlds[0][i] = z;
    }

    const uint loff = (uint)blockIdx.x * 1024u + (uint)(wid * 2) * 64u + (uint)lane;

    uint2 xa[2], xb[2];
    #pragma unroll
    for (int mt = 0; mt < 2; ++mt) xa[mt] = xin[(size_t)(loff + mt * 64u)];
    #pragma unroll
    for (int mt = 0; mt < 2; ++mt) xb[mt] = xin[(size_t)(8192u + loff + mt * 64u)];

    __syncthreads();

    const int rbase = n15 * 4 + 2 * (q & 1);
    const int shalf = q >> 1;
    const int woff  = n15 * 4 + q;

    auto step = [&](int t, uint2 (&X)[2]) {
        const int cur = t & 1, nxt = cur ^ 1;
        short8 bh[8];
        #pragma unroll
        for (int kt = 0; kt < 8; ++kt)
            bh[kt] = *(const short8*)&hlds[cur][(2 * kt + shalf) * 64 + rbase];
        f32x4 acc[2];
        #pragma unroll
        for (int mt = 0; mt < 2; ++mt) {
            acc[mt][0] = bflo2f(X[mt].x);
            acc[mt][1] = bfhi2f(X[mt].x);
            acc[mt][2] = bflo2f(X[mt].y);
            acc[mt][3] = bfhi2f(X[mt].y);
        }
        {
            const uint tp = (uint)((t + 2 < SEQ) ? (t + 2) : (SEQ - 1));
            const uint tb = tp * 8192u + loff;
            #pragma unroll
            for (int mt = 0; mt < 2; ++mt) X[mt] = xin[(size_t)(tb + mt * 64u)];
        }
        __builtin_amdgcn_s_setprio(1);
        #pragma unroll
        for (int kt = 0; kt < 8; ++kt)
            #pragma unroll
            for (int mt = 0; mt < 2; ++mt)
                acc[mt] = __builtin_amdgcn_mfma_f32_16x16x32_bf16(
                    wrec[mt][kt], bh[kt], acc[mt], 0, 0, 0);
        __builtin_amdgcn_s_setprio(0);
        #pragma unroll
        for (int mt = 0; mt < 2; ++mt) {
            float h0 = __builtin_amdgcn_rcpf(1.0f + __builtin_amdgcn_exp2f(-acc[mt][0]));
            float h1 = __builtin_amdgcn_rcpf(1.0f + __builtin_amdgcn_exp2f(-acc[mt][1]));
            float h2 = __builtin_amdgcn_rcpf(1.0f + __builtin_amdgcn_exp2f(-acc[mt][2]));
            float h3 = __builtin_amdgcn_rcpf(1.0f + __builtin_amdgcn_exp2f(-acc[mt][3]));
            uint2 w;
            w.x = pk_bf16(h0, h1);
            w.y = pk_bf16(h2, h3);
            hlds[nxt][(wid * 2 + mt) * 64 + woff] = w;
        }
        asm volatile("s_waitcnt lgkmcnt(0)" ::: "memory");
        __builtin_amdgcn_s_barrier();
    };

    #pragma unroll 1
    for (int t = 0; t < SEQ; t += 2) {
        step(t, xa);
        step(t + 1, xb);
    }

    short8 wout[8];
    float  bo[4];
    {
        const int row = wid * 16 + n15;
        #pragma unroll
        for (int kt = 0; kt < 8; ++kt)
            wout[kt] = load_wfrag_s(W_out, NH, row, kt * 32 + q * 8, 1.0f);
        #pragma unroll
        for (int r = 0; r < 4; ++r)
            bo[r] = b_out[wid * 16 + q * 4 + r];
    }
    f32x4 oacc;
    oacc[0] = bo[0]; oacc[1] = bo[1]; oacc[2] = bo[2]; oacc[3] = bo[3];
    #pragma unroll
    for (int kt = 0; kt < 8; ++kt) {
        short8 bh = *(const short8*)&hlds[0][(2 * kt + shalf) * 64 + rbase];
        oacc = __builtin_amdgcn_mfma_f32_16x16x32_bf16(wout[kt], bh, oacc, 0, 0, 0);
    }
    #pragma unroll
    for (int r = 0; r < 4; ++r) {
        const int o = wid * 16 + q * 4 + r;
        out[(size_t)(bblk + n15) * NOUT + o] = oacc[r];
    }
}

extern "C" void kernel_launch(void* const* d_in, const int* in_sizes, int n_in,
                              void* d_out, int out_size, void* d_ws, size_t ws_size,
                              hipStream_t stream) {
    const float* x     = (const float*)d_in[0];
    const float* W_in  = (const float*)d_in[1];
    const float* b_in  = (const float*)d_in[2];
    const float* W_rec = (const float*)d_in[3];
    const float* W_out = (const float*)d_in[4];
    const float* b_out = (const float*)d_in[5];
    float* out = (float*)d_out;

    const size_t xin_bytes  = (size_t)SEQ * BATCH * NH * sizeof(ushort);  // 134 MB
    const size_t flag_bytes = (size_t)NBLK * NCHUNK * sizeof(uint);       // 8 KB

    if (ws_size >= xin_bytes + flag_bytes) {
        uint2* xin  = (uint2*)d_ws;
        uint* flags = (uint*)((char*)d_ws + xin_bytes);
        hipMemsetAsync(flags, 0, flag_bytes, stream);
        // 8 consumers (dispatched first) + 2048 producers; 96 KB dynamic LDS
        // forces 1 block/CU so producers never co-reside with scan CUs.
        elman_fused<<<NBLK + NBLK * NCHUNK, 512, 96 * 1024, stream>>>(
            x, W_in, b_in, W_rec, W_out, b_out, out, xin, flags);
    } else if (ws_size >= xin_bytes) {
        uint2* xin = (uint2*)d_ws;
        dim3 g1(NBLK, SEQ / TCHUNK);
        xin_gemm<<<g1, 256, 0, stream>>>(x, W_in, b_in, xin);
        elman_scan<<<NBLK, 512, 0, stream>>>(xin, W_rec, W_out, b_out, out);
    }
}

// Round 8
// 1312.920 us; speedup vs baseline: 2.8112x; 1.0950x over previous
//
#include <hip/hip_runtime.h>
#include <hip/hip_bf16.h>

// Elman RNN, round 12: single-launch producer/consumer, fence-free gates.
// r11 post-mortem: overlap worked but consumer gates cost ~0.8 us each (acquire
// fence = vmcnt(0) drain + L1/L2 invalidate + cold reload + remote flag poll),
// degrading the scan 1109 -> 1315 us. Fix (no consumer fence at all):
//  - consumer xin loads = agent-scope RELAXED atomic loads (sc1: bypass the
//    non-coherent L1/L2, read MALL). Producer's threadfence(agent)+release flag
//    store already pushed the data to MALL -> flag==1 implies data visible to
//    sc1 loads. No invalidate, no prefetch drain.
//  - gate once per 64 steps: thread 0 relaxed-polls flags up to chunk t/8+8
//    (the window's prefetch horizon), then __syncthreads(). ~32 cheap gates.
// Producers and scan core unchanged from r11 (which passed).

#define BATCH 128
#define SEQ   2048
#define NIN   128
#define NH    256
#define NOUT  128

#define BTILE 16
#define NBLK  (BATCH / BTILE)      // 8
#define TCHUNK 8
#define NCHUNK (SEQ / TCHUNK)      // 256
#define GATE   64                  // consumer gate window (steps)
#define LOG2E 1.4426950408889634f

typedef __attribute__((ext_vector_type(8))) short short8;
typedef __attribute__((ext_vector_type(4))) float f32x4;

__device__ __forceinline__ ushort f2bf(float f) {
    union { float f; uint u; } v; v.f = f;
    uint r = v.u + 0x7fffu + ((v.u >> 16) & 1u);   // RNE
    return (ushort)(r >> 16);
}

// packed f32->bf16 RNE via builtin (m240: do not hand-write the asm)
__device__ __forceinline__ uint pk_bf16(float a, float b) {
    float2 p; p.x = a; p.y = b;
    __hip_bfloat162 h = __float22bfloat162_rn(p);
    union { __hip_bfloat162 h; uint u; } v; v.h = h; return v.u;
}

__device__ __forceinline__ short8 load_wfrag_s(const float* __restrict__ W, int ld,
                                               int row, int col, float scale) {
    const float4* p = (const float4*)(W + (size_t)row * ld + col);
    float4 a = p[0], b = p[1];
    union { short8 v; ushort u[8]; } r;
    r.u[0] = f2bf(a.x * scale); r.u[1] = f2bf(a.y * scale);
    r.u[2] = f2bf(a.z * scale); r.u[3] = f2bf(a.w * scale);
    r.u[4] = f2bf(b.x * scale); r.u[5] = f2bf(b.y * scale);
    r.u[6] = f2bf(b.z * scale); r.u[7] = f2bf(b.w * scale);
    return r.v;
}

__device__ __forceinline__ float bfhi2f(uint u) {
    union { uint u; float f; } v; v.u = u & 0xffff0000u; return v.f;
}
__device__ __forceinline__ float bflo2f(uint u) {
    union { uint u; float f; } v; v.u = u << 16; return v.f;
}

// =================== single-launch producer/consumer kernel ===================
__global__ __launch_bounds__(512, 2)
void elman_fused(const float* __restrict__ x,
                 const float* __restrict__ W_in,
                 const float* __restrict__ b_in,
                 const float* __restrict__ W_rec,
                 const float* __restrict__ W_out,
                 const float* __restrict__ b_out,
                 float* __restrict__ out,
                 uint2* __restrict__ xin,
                 uint*  __restrict__ flags) {
    const int tid  = threadIdx.x;
    const int lane = tid & 63;
    const int wid  = tid >> 6;          // 0..7
    const int n15  = lane & 15;
    const int q    = lane >> 4;

    __shared__ __align__(16) uint2 hlds[2][16 * 64];   // 16 KB static (consumer)

    if (blockIdx.x >= NBLK) {
        // ------------------------- producer -------------------------
        const int pid  = blockIdx.x - NBLK;
        const int c    = pid >> 3;
        const int b    = pid & 7;
        const int bblk = b * BTILE;
        const int t0   = c * TCHUNK;

        short8 win[2][4];
        float  bias[2][4];
        #pragma unroll
        for (int mt = 0; mt < 2; ++mt) {
            const int row = (wid * 2 + mt) * 16 + n15;
            #pragma unroll
            for (int kt = 0; kt < 4; ++kt)
                win[mt][kt] = load_wfrag_s(W_in, NIN, row, kt * 32 + q * 8, LOG2E);
            #pragma unroll
            for (int r = 0; r < 4; ++r)
                bias[mt][r] = LOG2E * b_in[(wid * 2 + mt) * 16 + q * 4 + r];
        }

        const float* xrow = x + ((size_t)(bblk + n15) * SEQ + t0) * NIN + q * 8;

        #pragma unroll 1
        for (int tt = 0; tt < TCHUNK; ++tt) {
            const float* xp = xrow + (size_t)tt * NIN;
            short8 bx[4];
            #pragma unroll
            for (int kt = 0; kt < 4; ++kt) {
                const float4* p = (const float4*)(xp + kt * 32);
                float4 a = p[0], bb = p[1];
                union { short8 v; uint u[4]; } r;
                r.u[0] = pk_bf16(a.x, a.y);
                r.u[1] = pk_bf16(a.z, a.w);
                r.u[2] = pk_bf16(bb.x, bb.y);
                r.u[3] = pk_bf16(bb.z, bb.w);
                bx[kt] = r.v;
            }
            f32x4 acc[2];
            #pragma unroll
            for (int mt = 0; mt < 2; ++mt) {
                acc[mt][0] = bias[mt][0]; acc[mt][1] = bias[mt][1];
                acc[mt][2] = bias[mt][2]; acc[mt][3] = bias[mt][3];
            }
            #pragma unroll
            for (int kt = 0; kt < 4; ++kt)
                #pragma unroll
                for (int mt = 0; mt < 2; ++mt)
                    acc[mt] = __builtin_amdgcn_mfma_f32_16x16x32_bf16(
                        win[mt][kt], bx[kt], acc[mt], 0, 0, 0);

            const uint tb = ((uint)(t0 + tt) * NBLK + (uint)b) * 16u;
            #pragma unroll
            for (int mt = 0; mt < 2; ++mt) {
                uint2 w;
                w.x = pk_bf16(acc[mt][0], acc[mt][1]);
                w.y = pk_bf16(acc[mt][2], acc[mt][3]);
                xin[(size_t)((tb + wid * 2 + mt) * 64u + lane)] = w;
            }
        }

        __syncthreads();                       // all stores issued
        if (tid == 0) {
            __threadfence();                   // agent fence: writeback to MALL
            __hip_atomic_store(&flags[b * NCHUNK + c], 1u,
                               __ATOMIC_RELEASE, __HIP_MEMORY_SCOPE_AGENT);
        }
        return;
    }

    // ------------------------- consumer: r9 scan + fence-free gates -------------
    const int  bblk  = blockIdx.x * BTILE;
    const uint fbase = (uint)blockIdx.x * NCHUNK;
    const unsigned long long* __restrict__ xin64 = (const unsigned long long*)xin;

    short8 wrec[2][8];
    #pragma unroll
    for (int mt = 0; mt < 2; ++mt) {
        const int row = (wid * 2 + mt) * 16 + n15;
        #pragma unroll
        for (int kt = 0; kt < 8; ++kt)
            wrec[mt][kt] = load_wfrag_s(W_rec, NH, row, kt * 32 + q * 8, LOG2E);
    }

    for (int i = tid; i < 16 * 64; i += 512) {
        uint2 z; z.x = 0u; z.y = 0u;
        hlds[0][i] = z;
    }

    const uint loff = (uint)blockIdx.x * 1024u + (uint)(wid * 2) * 64u + (uint)lane;

    int nf = 0;   // next unconfirmed flag (thread 0 only)
    // fence-free gate: poll flags up to 'target' (relaxed agent = sc1 read of
    // MALL; producer released data to MALL before setting flag), then barrier.
    auto gate_to = [&](int target) {
        if (target > NCHUNK - 1) target = NCHUNK - 1;
        if (tid == 0) {
            while (nf <= target) {
                while (__hip_atomic_load(&flags[fbase + (uint)nf],
                                         __ATOMIC_RELAXED,
                                         __HIP_MEMORY_SCOPE_AGENT) == 0u)
                    __builtin_amdgcn_s_sleep(2);
                ++nf;
            }
        }
        __syncthreads();
    };

    gate_to(GATE / TCHUNK + 1);   // chunks 0..8: covers window-0 incl. prefetch

    unsigned long long xa[2], xb[2];
    #pragma unroll
    for (int mt = 0; mt < 2; ++mt)
        xa[mt] = __hip_atomic_load(&xin64[loff + mt * 64u],
                                   __ATOMIC_RELAXED, __HIP_MEMORY_SCOPE_AGENT);
    #pragma unroll
    for (int mt = 0; mt < 2; ++mt)
        xb[mt] = __hip_atomic_load(&xin64[8192u + loff + mt * 64u],
                                   __ATOMIC_RELAXED, __HIP_MEMORY_SCOPE_AGENT);

    __syncthreads();

    const int rbase = n15 * 4 + 2 * (q & 1);
    const int shalf = q >> 1;
    const int woff  = n15 * 4 + q;

    auto step = [&](int t, unsigned long long (&X)[2]) {
        const int cur = t & 1, nxt = cur ^ 1;

        short8 bh[8];
        #pragma unroll
        for (int kt = 0; kt < 8; ++kt)
            bh[kt] = *(const short8*)&hlds[cur][(2 * kt + shalf) * 64 + rbase];

        f32x4 acc[2];
        #pragma unroll
        for (int mt = 0; mt < 2; ++mt) {
            const uint lo = (uint)X[mt], hi = (uint)(X[mt] >> 32);
            acc[mt][0] = bflo2f(lo);
            acc[mt][1] = bfhi2f(lo);
            acc[mt][2] = bflo2f(hi);
            acc[mt][3] = bfhi2f(hi);
        }

        {   // prefetch xin_{t+2} (sc1, floats across the lgkm-only barrier)
            const uint tp = (uint)((t + 2 < SEQ) ? (t + 2) : (SEQ - 1));
            const uint tb = tp * 8192u + loff;
            #pragma unroll
            for (int mt = 0; mt < 2; ++mt)
                X[mt] = __hip_atomic_load(&xin64[tb + mt * 64u],
                                          __ATOMIC_RELAXED,
                                          __HIP_MEMORY_SCOPE_AGENT);
        }

        __builtin_amdgcn_s_setprio(1);
        #pragma unroll
        for (int kt = 0; kt < 8; ++kt)
            #pragma unroll
            for (int mt = 0; mt < 2; ++mt)
                acc[mt] = __builtin_amdgcn_mfma_f32_16x16x32_bf16(
                    wrec[mt][kt], bh[kt], acc[mt], 0, 0, 0);
        __builtin_amdgcn_s_setprio(0);

        #pragma unroll
        for (int mt = 0; mt < 2; ++mt) {
            float h0 = __builtin_amdgcn_rcpf(1.0f + __builtin_amdgcn_exp2f(-acc[mt][0]));
            float h1 = __builtin_amdgcn_rcpf(1.0f + __builtin_amdgcn_exp2f(-acc[mt][1]));
            float h2 = __builtin_amdgcn_rcpf(1.0f + __builtin_amdgcn_exp2f(-acc[mt][2]));
            float h3 = __builtin_amdgcn_rcpf(1.0f + __builtin_amdgcn_exp2f(-acc[mt][3]));
            uint2 w;
            w.x = pk_bf16(h0, h1);
            w.y = pk_bf16(h2, h3);
            hlds[nxt][(wid * 2 + mt) * 64 + woff] = w;
        }

        asm volatile("s_waitcnt lgkmcnt(0)" ::: "memory");
        __builtin_amdgcn_s_barrier();
    };

    #pragma unroll 1
    for (int t = 0; t < SEQ; t += 2) {
        if (t && (t & (GATE - 1)) == 0)
            gate_to((t >> 3) + GATE / TCHUNK / 8 + 8);   // chunk horizon t/8+8
        step(t, xa);
        step(t + 1, xb);
    }

    // ---- output projection from hlds[0] (SEQ even): wave wid owns m-tile wid ----
    short8 wout[8];
    float  bo[4];
    {
        const int row = wid * 16 + n15;
        #pragma unroll
        for (int kt = 0; kt < 8; ++kt)
            wout[kt] = load_wfrag_s(W_out, NH, row, kt * 32 + q * 8, 1.0f);
        #pragma unroll
        for (int r = 0; r < 4; ++r)
            bo[r] = b_out[wid * 16 + q * 4 + r];
    }
    f32x4 oacc;
    oacc[0] = bo[0]; oacc[1] = bo[1]; oacc[2] = bo[2]; oacc[3] = bo[3];
    #pragma unroll
    for (int kt = 0; kt < 8; ++kt) {
        short8 bh = *(const short8*)&hlds[0][(2 * kt + shalf) * 64 + rbase];
        oacc = __builtin_amdgcn_mfma_f32_16x16x32_bf16(wout[kt], bh, oacc, 0, 0, 0);
    }
    #pragma unroll
    for (int r = 0; r < 4; ++r) {
        const int o = wid * 16 + q * 4 + r;
        out[(size_t)(bblk + n15) * NOUT + o] = oacc[r];
    }
}

// =================== fallback: exact r9 two-kernel path ===================
__global__ __launch_bounds__(256, 2)
void xin_gemm(const float* __restrict__ x,
              const float* __restrict__ W_in,
              const float* __restrict__ b_in,
              uint2* __restrict__ xin) {
    const int tid  = threadIdx.x;
    const int lane = tid & 63;
    const int wid  = tid >> 6;
    const int n15  = lane & 15;
    const int q    = lane >> 4;
    const int bblk = blockIdx.x * BTILE;
    const int t0   = blockIdx.y * TCHUNK;

    short8 win[4][4];
    float  bias[4][4];
    #pragma unroll
    for (int mt = 0; mt < 4; ++mt) {
        const int row = (wid * 4 + mt) * 16 + n15;
        #pragma unroll
        for (int kt = 0; kt < 4; ++kt)
            win[mt][kt] = load_wfrag_s(W_in, NIN, row, kt * 32 + q * 8, LOG2E);
        #pragma unroll
        for (int r = 0; r < 4; ++r)
            bias[mt][r] = LOG2E * b_in[(wid * 4 + mt) * 16 + q * 4 + r];
    }

    const float* xrow = x + ((size_t)(bblk + n15) * SEQ + t0) * NIN + q * 8;

    #pragma unroll 1
    for (int tt = 0; tt < TCHUNK; ++tt) {
        const float* xp = xrow + (size_t)tt * NIN;
        short8 bx[4];
        #pragma unroll
        for (int kt = 0; kt < 4; ++kt) {
            const float4* p = (const float4*)(xp + kt * 32);
            float4 a = p[0], b = p[1];
            union { short8 v; uint u[4]; } r;
            r.u[0] = pk_bf16(a.x, a.y);
            r.u[1] = pk_bf16(a.z, a.w);
            r.u[2] = pk_bf16(b.x, b.y);
            r.u[3] = pk_bf16(b.z, b.w);
            bx[kt] = r.v;
        }
        f32x4 acc[4];
        #pragma unroll
        for (int mt = 0; mt < 4; ++mt) {
            acc[mt][0] = bias[mt][0]; acc[mt][1] = bias[mt][1];
            acc[mt][2] = bias[mt][2]; acc[mt][3] = bias[mt][3];
        }
        #pragma unroll
        for (int kt = 0; kt < 4; ++kt)
            #pragma unroll
            for (int mt = 0; mt < 4; ++mt)
                acc[mt] = __builtin_amdgcn_mfma_f32_16x16x32_bf16(
                    win[mt][kt], bx[kt], acc[mt], 0, 0, 0);

        const uint tb = ((uint)(t0 + tt) * NBLK + blockIdx.x) * 16u;
        #pragma unroll
        for (int mt = 0; mt < 4; ++mt) {
            uint2 w;
            w.x = pk_bf16(acc[mt][0], acc[mt][1]);
            w.y = pk_bf16(acc[mt][2], acc[mt][3]);
            xin[(size_t)((tb + wid * 4 + mt) * 64u + lane)] = w;
        }
    }
}

__global__ __launch_bounds__(512, 2)
void elman_scan(const uint2* __restrict__ xin,
                const float* __restrict__ W_rec,
                const float* __restrict__ W_out,
                const float* __restrict__ b_out,
                float* __restrict__ out) {
    const int tid  = threadIdx.x;
    const int lane = tid & 63;
    const int wid  = tid >> 6;
    const int n15  = lane & 15;
    const int q    = lane >> 4;
    const int bblk = blockIdx.x * BTILE;

    __shared__ __align__(16) uint2 hlds[2][16 * 64];

    short8 wrec[2][8];
    #pragma unroll
    for (int mt = 0; mt < 2; ++mt) {
        const int row = (wid * 2 + mt) * 16 + n15;
        #pragma unroll
        for (int kt = 0; kt < 8; ++kt)
            wrec[mt][kt] = load_wfrag_s(W_rec, NH, row, kt * 32 + q * 8, LOG2E);
    }

    for (int i = tid; i < 16 * 64; i += 512) {
        uint2 z; z.x = 0u; z.y = 0u;
        hlds[0][i] = z;
    }

    const uint loff = (uint)blockIdx.x * 1024u + (uint)(wid * 2) * 64u + (uint)lane;

    uint2 xa[2], xb[2];
    #pragma unroll
    for (int mt = 0; mt < 2; ++mt) xa[mt] = xin[(size_t)(loff + mt * 64u)];
    #pragma unroll
    for (int mt = 0; mt < 2; ++mt) xb[mt] = xin[(size_t)(8192u + loff + mt * 64u)];

    __syncthreads();

    const int rbase = n15 * 4 + 2 * (q & 1);
    const int shalf = q >> 1;
    const int woff  = n15 * 4 + q;

    auto step = [&](int t, uint2 (&X)[2]) {
        const int cur = t & 1, nxt = cur ^ 1;
        short8 bh[8];
        #pragma unroll
        for (int kt = 0; kt < 8; ++kt)
            bh[kt] = *(const short8*)&hlds[cur][(2 * kt + shalf) * 64 + rbase];
        f32x4 acc[2];
        #pragma unroll
        for (int mt = 0; mt < 2; ++mt) {
            acc[mt][0] = bflo2f(X[mt].x);
            acc[mt][1] = bfhi2f(X[mt].x);
            acc[mt][2] = bflo2f(X[mt].y);
            acc[mt][3] = bfhi2f(X[mt].y);
        }
        {
            const uint tp = (uint)((t + 2 < SEQ) ? (t + 2) : (SEQ - 1));
            const uint tb = tp * 8192u + loff;
            #pragma unroll
            for (int mt = 0; mt < 2; ++mt) X[mt] = xin[(size_t)(tb + mt * 64u)];
        }
        __builtin_amdgcn_s_setprio(1);
        #pragma unroll
        for (int kt = 0; kt < 8; ++kt)
            #pragma unroll
            for (int mt = 0; mt < 2; ++mt)
                acc[mt] = __builtin_amdgcn_mfma_f32_16x16x32_bf16(
                    wrec[mt][kt], bh[kt], acc[mt], 0, 0, 0);
        __builtin_amdgcn_s_setprio(0);
        #pragma unroll
        for (int mt = 0; mt < 2; ++mt) {
            float h0 = __builtin_amdgcn_rcpf(1.0f + __builtin_amdgcn_exp2f(-acc[mt][0]));
            float h1 = __builtin_amdgcn_rcpf(1.0f + __builtin_amdgcn_exp2f(-acc[mt][1]));
            float h2 = __builtin_amdgcn_rcpf(1.0f + __builtin_amdgcn_exp2f(-acc[mt][2]));
            float h3 = __builtin_amdgcn_rcpf(1.0f + __builtin_amdgcn_exp2f(-acc[mt][3]));
            uint2 w;
            w.x = pk_bf16(h0, h1);
            w.y = pk_bf16(h2, h3);
            hlds[nxt][(wid * 2 + mt) * 64 + woff] = w;
        }
        asm volatile("s_waitcnt lgkmcnt(0)" ::: "memory");
        __builtin_amdgcn_s_barrier();
    };

    #pragma unroll 1
    for (int t = 0; t < SEQ; t += 2) {
        step(t, xa);
        step(t + 1, xb);
    }

    short8 wout[8];
    float  bo[4];
    {
        const int row = wid * 16 + n15;
        #pragma unroll
        for (int kt = 0; kt < 8; ++kt)
            wout[kt] = load_wfrag_s(W_out, NH, row, kt * 32 + q * 8, 1.0f);
        #pragma unroll
        for (int r = 0; r < 4; ++r)
            bo[r] = b_out[wid * 16 + q * 4 + r];
    }
    f32x4 oacc;
    oacc[0] = bo[0]; oacc[1] = bo[1]; oacc[2] = bo[2]; oacc[3] = bo[3];
    #pragma unroll
    for (int kt = 0; kt < 8; ++kt) {
        short8 bh = *(const short8*)&hlds[0][(2 * kt + shalf) * 64 + rbase];
        oacc = __builtin_amdgcn_mfma_f32_16x16x32_bf16(wout[kt], bh, oacc, 0, 0, 0);
    }
    #pragma unroll
    for (int r = 0; r < 4; ++r) {
        const int o = wid * 16 + q * 4 + r;
        out[(size_t)(bblk + n15) * NOUT + o] = oacc[r];
    }
}

extern "C" void kernel_launch(void* const* d_in, const int* in_sizes, int n_in,
                              void* d_out, int out_size, void* d_ws, size_t ws_size,
                              hipStream_t stream) {
    const float* x     = (const float*)d_in[0];
    const float* W_in  = (const float*)d_in[1];
    const float* b_in  = (const float*)d_in[2];
    const float* W_rec = (const float*)d_in[3];
    const float* W_out = (const float*)d_in[4];
    const float* b_out = (const float*)d_in[5];
    float* out = (float*)d_out;

    const size_t xin_bytes  = (size_t)SEQ * BATCH * NH * sizeof(ushort);  // 134 MB
    const size_t flag_bytes = (size_t)NBLK * NCHUNK * sizeof(uint);       // 8 KB

    if (ws_size >= xin_bytes + flag_bytes) {
        uint2* xin  = (uint2*)d_ws;
        uint* flags = (uint*)((char*)d_ws + xin_bytes);
        hipMemsetAsync(flags, 0, flag_bytes, stream);
        // 8 consumers (dispatched first) + 2048 producers; 96 KB dynamic LDS
        // forces 1 block/CU so producers never co-reside with scan CUs.
        elman_fused<<<NBLK + NBLK * NCHUNK, 512, 96 * 1024, stream>>>(
            x, W_in, b_in, W_rec, W_out, b_out, out, xin, flags);
    } else if (ws_size >= xin_bytes) {
        uint2* xin = (uint2*)d_ws;
        dim3 g1(NBLK, SEQ / TCHUNK);
        xin_gemm<<<g1, 256, 0, stream>>>(x, W_in, b_in, xin);
        elman_scan<<<NBLK, 512, 0, stream>>>(xin, W_rec, W_out, b_out, out);
    }
}

// Round 9
// 1279.703 us; speedup vs baseline: 2.8842x; 1.0260x over previous
//
#include <hip/hip_runtime.h>
#include <hip/hip_bf16.h>

// Elman RNN, round 13: r12 + wave-parallel flag polling.
// r12 post-mortem: fence-free gates worked (1315 -> 1186 us dispatch; total 1313,
// best). Residue vs pure scan (1109) ~= 77 us ~= 256 flags polled SERIALLY by
// thread 0 at ~600 cyc MALL latency each. Fix: wave-0 parallel poll — lanes
// 0..63 each load one flag of the gate's [nf..target] range (<=10), __all ->
// uniform advance; one MALL round-trip per gate (32 gates x ~0.3 us ~ 10 us).
// Everything else byte-identical to r12 (passed): producers + release flag,
// consumer sc1 relaxed data loads, 64-step gate cadence, scan core from r9.

#define BATCH 128
#define SEQ   2048
#define NIN   128
#define NH    256
#define NOUT  128

#define BTILE 16
#define NBLK  (BATCH / BTILE)      // 8
#define TCHUNK 8
#define NCHUNK (SEQ / TCHUNK)      // 256
#define GATE   64                  // consumer gate window (steps)
#define LOG2E 1.4426950408889634f

typedef __attribute__((ext_vector_type(8))) short short8;
typedef __attribute__((ext_vector_type(4))) float f32x4;

__device__ __forceinline__ ushort f2bf(float f) {
    union { float f; uint u; } v; v.f = f;
    uint r = v.u + 0x7fffu + ((v.u >> 16) & 1u);   // RNE
    return (ushort)(r >> 16);
}

// packed f32->bf16 RNE via builtin (m240: do not hand-write the asm)
__device__ __forceinline__ uint pk_bf16(float a, float b) {
    float2 p; p.x = a; p.y = b;
    __hip_bfloat162 h = __float22bfloat162_rn(p);
    union { __hip_bfloat162 h; uint u; } v; v.h = h; return v.u;
}

__device__ __forceinline__ short8 load_wfrag_s(const float* __restrict__ W, int ld,
                                               int row, int col, float scale) {
    const float4* p = (const float4*)(W + (size_t)row * ld + col);
    float4 a = p[0], b = p[1];
    union { short8 v; ushort u[8]; } r;
    r.u[0] = f2bf(a.x * scale); r.u[1] = f2bf(a.y * scale);
    r.u[2] = f2bf(a.z * scale); r.u[3] = f2bf(a.w * scale);
    r.u[4] = f2bf(b.x * scale); r.u[5] = f2bf(b.y * scale);
    r.u[6] = f2bf(b.z * scale); r.u[7] = f2bf(b.w * scale);
    return r.v;
}

__device__ __forceinline__ float bfhi2f(uint u) {
    union { uint u; float f; } v; v.u = u & 0xffff0000u; return v.f;
}
__device__ __forceinline__ float bflo2f(uint u) {
    union { uint u; float f; } v; v.u = u << 16; return v.f;
}

// =================== single-launch producer/consumer kernel ===================
__global__ __launch_bounds__(512, 2)
void elman_fused(const float* __restrict__ x,
                 const float* __restrict__ W_in,
                 const float* __restrict__ b_in,
                 const float* __restrict__ W_rec,
                 const float* __restrict__ W_out,
                 const float* __restrict__ b_out,
                 float* __restrict__ out,
                 uint2* __restrict__ xin,
                 uint*  __restrict__ flags) {
    const int tid  = threadIdx.x;
    const int lane = tid & 63;
    const int wid  = tid >> 6;          // 0..7
    const int n15  = lane & 15;
    const int q    = lane >> 4;

    __shared__ __align__(16) uint2 hlds[2][16 * 64];   // 16 KB static (consumer)

    if (blockIdx.x >= NBLK) {
        // ------------------------- producer -------------------------
        const int pid  = blockIdx.x - NBLK;
        const int c    = pid >> 3;
        const int b    = pid & 7;
        const int bblk = b * BTILE;
        const int t0   = c * TCHUNK;

        short8 win[2][4];
        float  bias[2][4];
        #pragma unroll
        for (int mt = 0; mt < 2; ++mt) {
            const int row = (wid * 2 + mt) * 16 + n15;
            #pragma unroll
            for (int kt = 0; kt < 4; ++kt)
                win[mt][kt] = load_wfrag_s(W_in, NIN, row, kt * 32 + q * 8, LOG2E);
            #pragma unroll
            for (int r = 0; r < 4; ++r)
                bias[mt][r] = LOG2E * b_in[(wid * 2 + mt) * 16 + q * 4 + r];
        }

        const float* xrow = x + ((size_t)(bblk + n15) * SEQ + t0) * NIN + q * 8;

        #pragma unroll 1
        for (int tt = 0; tt < TCHUNK; ++tt) {
            const float* xp = xrow + (size_t)tt * NIN;
            short8 bx[4];
            #pragma unroll
            for (int kt = 0; kt < 4; ++kt) {
                const float4* p = (const float4*)(xp + kt * 32);
                float4 a = p[0], bb = p[1];
                union { short8 v; uint u[4]; } r;
                r.u[0] = pk_bf16(a.x, a.y);
                r.u[1] = pk_bf16(a.z, a.w);
                r.u[2] = pk_bf16(bb.x, bb.y);
                r.u[3] = pk_bf16(bb.z, bb.w);
                bx[kt] = r.v;
            }
            f32x4 acc[2];
            #pragma unroll
            for (int mt = 0; mt < 2; ++mt) {
                acc[mt][0] = bias[mt][0]; acc[mt][1] = bias[mt][1];
                acc[mt][2] = bias[mt][2]; acc[mt][3] = bias[mt][3];
            }
            #pragma unroll
            for (int kt = 0; kt < 4; ++kt)
                #pragma unroll
                for (int mt = 0; mt < 2; ++mt)
                    acc[mt] = __builtin_amdgcn_mfma_f32_16x16x32_bf16(
                        win[mt][kt], bx[kt], acc[mt], 0, 0, 0);

            const uint tb = ((uint)(t0 + tt) * NBLK + (uint)b) * 16u;
            #pragma unroll
            for (int mt = 0; mt < 2; ++mt) {
                uint2 w;
                w.x = pk_bf16(acc[mt][0], acc[mt][1]);
                w.y = pk_bf16(acc[mt][2], acc[mt][3]);
                xin[(size_t)((tb + wid * 2 + mt) * 64u + lane)] = w;
            }
        }

        __syncthreads();                       // all stores issued
        if (tid == 0) {
            __threadfence();                   // agent fence: writeback to MALL
            __hip_atomic_store(&flags[b * NCHUNK + c], 1u,
                               __ATOMIC_RELEASE, __HIP_MEMORY_SCOPE_AGENT);
        }
        return;
    }

    // ------------------------- consumer: r9 scan + parallel gates ---------------
    const int  bblk  = blockIdx.x * BTILE;
    const uint fbase = (uint)blockIdx.x * NCHUNK;
    const unsigned long long* __restrict__ xin64 = (const unsigned long long*)xin;

    short8 wrec[2][8];
    #pragma unroll
    for (int mt = 0; mt < 2; ++mt) {
        const int row = (wid * 2 + mt) * 16 + n15;
        #pragma unroll
        for (int kt = 0; kt < 8; ++kt)
            wrec[mt][kt] = load_wfrag_s(W_rec, NH, row, kt * 32 + q * 8, LOG2E);
    }

    for (int i = tid; i < 16 * 64; i += 512) {
        uint2 z; z.x = 0u; z.y = 0u;
        hlds[0][i] = z;
    }

    const uint loff = (uint)blockIdx.x * 1024u + (uint)(wid * 2) * 64u + (uint)lane;

    int nf = 0;   // next unconfirmed flag (wave 0; uniform across its lanes)
    // wave-parallel fence-free gate: lanes of wave 0 each load one flag of
    // [nf..target] (relaxed agent = sc1 MALL read), __all -> uniform advance.
    // One MALL round-trip per gate instead of (target-nf) serial reads.
    auto gate_to = [&](int target) {
        if (target > NCHUNK - 1) target = NCHUNK - 1;
        if (wid == 0) {
            while (nf <= target) {
                const int idx = nf + lane;
                bool ok = (idx > target) ||
                          (__hip_atomic_load(&flags[fbase + (uint)idx],
                                             __ATOMIC_RELAXED,
                                             __HIP_MEMORY_SCOPE_AGENT) != 0u);
                if (__all(ok)) nf = target + 1;
                else __builtin_amdgcn_s_sleep(4);
            }
        }
        __syncthreads();
    };

    gate_to(GATE / TCHUNK + 1);   // chunks 0..9: covers window-0 incl. prefetch

    unsigned long long xa[2], xb[2];
    #pragma unroll
    for (int mt = 0; mt < 2; ++mt)
        xa[mt] = __hip_atomic_load(&xin64[loff + mt * 64u],
                                   __ATOMIC_RELAXED, __HIP_MEMORY_SCOPE_AGENT);
    #pragma unroll
    for (int mt = 0; mt < 2; ++mt)
        xb[mt] = __hip_atomic_load(&xin64[8192u + loff + mt * 64u],
                                   __ATOMIC_RELAXED, __HIP_MEMORY_SCOPE_AGENT);

    __syncthreads();

    const int rbase = n15 * 4 + 2 * (q & 1);
    const int shalf = q >> 1;
    const int woff  = n15 * 4 + q;

    auto step = [&](int t, unsigned long long (&X)[2]) {
        const int cur = t & 1, nxt = cur ^ 1;

        short8 bh[8];
        #pragma unroll
        for (int kt = 0; kt < 8; ++kt)
            bh[kt] = *(const short8*)&hlds[cur][(2 * kt + shalf) * 64 + rbase];

        f32x4 acc[2];
        #pragma unroll
        for (int mt = 0; mt < 2; ++mt) {
            const uint lo = (uint)X[mt], hi = (uint)(X[mt] >> 32);
            acc[mt][0] = bflo2f(lo);
            acc[mt][1] = bfhi2f(lo);
            acc[mt][2] = bflo2f(hi);
            acc[mt][3] = bfhi2f(hi);
        }

        {   // prefetch xin_{t+2} (sc1, floats across the lgkm-only barrier)
            const uint tp = (uint)((t + 2 < SEQ) ? (t + 2) : (SEQ - 1));
            const uint tb = tp * 8192u + loff;
            #pragma unroll
            for (int mt = 0; mt < 2; ++mt)
                X[mt] = __hip_atomic_load(&xin64[tb + mt * 64u],
                                          __ATOMIC_RELAXED,
                                          __HIP_MEMORY_SCOPE_AGENT);
        }

        __builtin_amdgcn_s_setprio(1);
        #pragma unroll
        for (int kt = 0; kt < 8; ++kt)
            #pragma unroll
            for (int mt = 0; mt < 2; ++mt)
                acc[mt] = __builtin_amdgcn_mfma_f32_16x16x32_bf16(
                    wrec[mt][kt], bh[kt], acc[mt], 0, 0, 0);
        __builtin_amdgcn_s_setprio(0);

        #pragma unroll
        for (int mt = 0; mt < 2; ++mt) {
            float h0 = __builtin_amdgcn_rcpf(1.0f + __builtin_amdgcn_exp2f(-acc[mt][0]));
            float h1 = __builtin_amdgcn_rcpf(1.0f + __builtin_amdgcn_exp2f(-acc[mt][1]));
            float h2 = __builtin_amdgcn_rcpf(1.0f + __builtin_amdgcn_exp2f(-acc[mt][2]));
            float h3 = __builtin_amdgcn_rcpf(1.0f + __builtin_amdgcn_exp2f(-acc[mt][3]));
            uint2 w;
            w.x = pk_bf16(h0, h1);
            w.y = pk_bf16(h2, h3);
            hlds[nxt][(wid * 2 + mt) * 64 + woff] = w;
        }

        asm volatile("s_waitcnt lgkmcnt(0)" ::: "memory");
        __builtin_amdgcn_s_barrier();
    };

    #pragma unroll 1
    for (int t = 0; t < SEQ; t += 2) {
        if (t && (t & (GATE - 1)) == 0)
            gate_to((t >> 3) + GATE / TCHUNK / 8 + 8);   // chunk horizon t/8+9
        step(t, xa);
        step(t + 1, xb);
    }

    // ---- output projection from hlds[0] (SEQ even): wave wid owns m-tile wid ----
    short8 wout[8];
    float  bo[4];
    {
        const int row = wid * 16 + n15;
        #pragma unroll
        for (int kt = 0; kt < 8; ++kt)
            wout[kt] = load_wfrag_s(W_out, NH, row, kt * 32 + q * 8, 1.0f);
        #pragma unroll
        for (int r = 0; r < 4; ++r)
            bo[r] = b_out[wid * 16 + q * 4 + r];
    }
    f32x4 oacc;
    oacc[0] = bo[0]; oacc[1] = bo[1]; oacc[2] = bo[2]; oacc[3] = bo[3];
    #pragma unroll
    for (int kt = 0; kt < 8; ++kt) {
        short8 bh = *(const short8*)&hlds[0][(2 * kt + shalf) * 64 + rbase];
        oacc = __builtin_amdgcn_mfma_f32_16x16x32_bf16(wout[kt], bh, oacc, 0, 0, 0);
    }
    #pragma unroll
    for (int r = 0; r < 4; ++r) {
        const int o = wid * 16 + q * 4 + r;
        out[(size_t)(bblk + n15) * NOUT + o] = oacc[r];
    }
}

// =================== fallback: exact r9 two-kernel path ===================
__global__ __launch_bounds__(256, 2)
void xin_gemm(const float* __restrict__ x,
              const float* __restrict__ W_in,
              const float* __restrict__ b_in,
              uint2* __restrict__ xin) {
    const int tid  = threadIdx.x;
    const int lane = tid & 63;
    const int wid  = tid >> 6;
    const int n15  = lane & 15;
    const int q    = lane >> 4;
    const int bblk = blockIdx.x * BTILE;
    const int t0   = blockIdx.y * TCHUNK;

    short8 win[4][4];
    float  bias[4][4];
    #pragma unroll
    for (int mt = 0; mt < 4; ++mt) {
        const int row = (wid * 4 + mt) * 16 + n15;
        #pragma unroll
        for (int kt = 0; kt < 4; ++kt)
            win[mt][kt] = load_wfrag_s(W_in, NIN, row, kt * 32 + q * 8, LOG2E);
        #pragma unroll
        for (int r = 0; r < 4; ++r)
            bias[mt][r] = LOG2E * b_in[(wid * 4 + mt) * 16 + q * 4 + r];
    }

    const float* xrow = x + ((size_t)(bblk + n15) * SEQ + t0) * NIN + q * 8;

    #pragma unroll 1
    for (int tt = 0; tt < TCHUNK; ++tt) {
        const float* xp = xrow + (size_t)tt * NIN;
        short8 bx[4];
        #pragma unroll
        for (int kt = 0; kt < 4; ++kt) {
            const float4* p = (const float4*)(xp + kt * 32);
            float4 a = p[0], b = p[1];
            union { short8 v; uint u[4]; } r;
            r.u[0] = pk_bf16(a.x, a.y);
            r.u[1] = pk_bf16(a.z, a.w);
            r.u[2] = pk_bf16(b.x, b.y);
            r.u[3] = pk_bf16(b.z, b.w);
            bx[kt] = r.v;
        }
        f32x4 acc[4];
        #pragma unroll
        for (int mt = 0; mt < 4; ++mt) {
            acc[mt][0] = bias[mt][0]; acc[mt][1] = bias[mt][1];
            acc[mt][2] = bias[mt][2]; acc[mt][3] = bias[mt][3];
        }
        #pragma unroll
        for (int kt = 0; kt < 4; ++kt)
            #pragma unroll
            for (int mt = 0; mt < 4; ++mt)
                acc[mt] = __builtin_amdgcn_mfma_f32_16x16x32_bf16(
                    win[mt][kt], bx[kt], acc[mt], 0, 0, 0);

        const uint tb = ((uint)(t0 + tt) * NBLK + blockIdx.x) * 16u;
        #pragma unroll
        for (int mt = 0; mt < 4; ++mt) {
            uint2 w;
            w.x = pk_bf16(acc[mt][0], acc[mt][1]);
            w.y = pk_bf16(acc[mt][2], acc[mt][3]);
            xin[(size_t)((tb + wid * 4 + mt) * 64u + lane)] = w;
        }
    }
}

__global__ __launch_bounds__(512, 2)
void elman_scan(const uint2* __restrict__ xin,
                const float* __restrict__ W_rec,
                const float* __restrict__ W_out,
                const float* __restrict__ b_out,
                float* __restrict__ out) {
    const int tid  = threadIdx.x;
    const int lane = tid & 63;
    const int wid  = tid >> 6;
    const int n15  = lane & 15;
    const int q    = lane >> 4;
    const int bblk = blockIdx.x * BTILE;

    __shared__ __align__(16) uint2 hlds[2][16 * 64];

    short8 wrec[2][8];
    #pragma unroll
    for (int mt = 0; mt < 2; ++mt) {
        const int row = (wid * 2 + mt) * 16 + n15;
        #pragma unroll
        for (int kt = 0; kt < 8; ++kt)
            wrec[mt][kt] = load_wfrag_s(W_rec, NH, row, kt * 32 + q * 8, LOG2E);
    }

    for (int i = tid; i < 16 * 64; i += 512) {
        uint2 z; z.x = 0u; z.y = 0u;
        hlds[0][i] = z;
    }

    const uint loff = (uint)blockIdx.x * 1024u + (uint)(wid * 2) * 64u + (uint)lane;

    uint2 xa[2], xb[2];
    #pragma unroll
    for (int mt = 0; mt < 2; ++mt) xa[mt] = xin[(size_t)(loff + mt * 64u)];
    #pragma unroll
    for (int mt = 0; mt < 2; ++mt) xb[mt] = xin[(size_t)(8192u + loff + mt * 64u)];

    __syncthreads();

    const int rbase = n15 * 4 + 2 * (q & 1);
    const int shalf = q >> 1;
    const int woff  = n15 * 4 + q;

    auto step = [&](int t, uint2 (&X)[2]) {
        const int cur = t & 1, nxt = cur ^ 1;
        short8 bh[8];
        #pragma unroll
        for (int kt = 0; kt < 8; ++kt)
            bh[kt] = *(const short8*)&hlds[cur][(2 * kt + shalf) * 64 + rbase];
        f32x4 acc[2];
        #pragma unroll
        for (int mt = 0; mt < 2; ++mt) {
            acc[mt][0] = bflo2f(X[mt].x);
            acc[mt][1] = bfhi2f(X[mt].x);
            acc[mt][2] = bflo2f(X[mt].y);
            acc[mt][3] = bfhi2f(X[mt].y);
        }
        {
            const uint tp = (uint)((t + 2 < SEQ) ? (t + 2) : (SEQ - 1));
            const uint tb = tp * 8192u + loff;
            #pragma unroll
            for (int mt = 0; mt < 2; ++mt) X[mt] = xin[(size_t)(tb + mt * 64u)];
        }
        __builtin_amdgcn_s_setprio(1);
        #pragma unroll
        for (int kt = 0; kt < 8; ++kt)
            #pragma unroll
            for (int mt = 0; mt < 2; ++mt)
                acc[mt] = __builtin_amdgcn_mfma_f32_16x16x32_bf16(
                    wrec[mt][kt], bh[kt], acc[mt], 0, 0, 0);
        __builtin_amdgcn_s_setprio(0);
        #pragma unroll
        for (int mt = 0; mt < 2; ++mt) {
            float h0 = __builtin_amdgcn_rcpf(1.0f + __builtin_amdgcn_exp2f(-acc[mt][0]));
            float h1 = __builtin_amdgcn_rcpf(1.0f + __builtin_amdgcn_exp2f(-acc[mt][1]));
            float h2 = __builtin_amdgcn_rcpf(1.0f + __builtin_amdgcn_exp2f(-acc[mt][2]));
            float h3 = __builtin_amdgcn_rcpf(1.0f + __builtin_amdgcn_exp2f(-acc[mt][3]));
            uint2 w;
            w.x = pk_bf16(h0, h1);
            w.y = pk_bf16(h2, h3);
            hlds[nxt][(wid * 2 + mt) * 64 + woff] = w;
        }
        asm volatile("s_waitcnt lgkmcnt(0)" ::: "memory");
        __builtin_amdgcn_s_barrier();
    };

    #pragma unroll 1
    for (int t = 0; t < SEQ; t += 2) {
        step(t, xa);
        step(t + 1, xb);
    }

    short8 wout[8];
    float  bo[4];
    {
        const int row = wid * 16 + n15;
        #pragma unroll
        for (int kt = 0; kt < 8; ++kt)
            wout[kt] = load_wfrag_s(W_out, NH, row, kt * 32 + q * 8, 1.0f);
        #pragma unroll
        for (int r = 0; r < 4; ++r)
            bo[r] = b_out[wid * 16 + q * 4 + r];
    }
    f32x4 oacc;
    oacc[0] = bo[0]; oacc[1] = bo[1]; oacc[2] = bo[2]; oacc[3] = bo[3];
    #pragma unroll
    for (int kt = 0; kt < 8; ++kt) {
        short8 bh = *(const short8*)&hlds[0][(2 * kt + shalf) * 64 + rbase];
        oacc = __builtin_amdgcn_mfma_f32_16x16x32_bf16(wout[kt], bh, oacc, 0, 0, 0);
    }
    #pragma unroll
    for (int r = 0; r < 4; ++r) {
        const int o = wid * 16 + q * 4 + r;
        out[(size_t)(bblk + n15) * NOUT + o] = oacc[r];
    }
}

extern "C" void kernel_launch(void* const* d_in, const int* in_sizes, int n_in,
                              void* d_out, int out_size, void* d_ws, size_t ws_size,
                              hipStream_t stream) {
    const float* x     = (const float*)d_in[0];
    const float* W_in  = (const float*)d_in[1];
    const float* b_in  = (const float*)d_in[2];
    const float* W_rec = (const float*)d_in[3];
    const float* W_out = (const float*)d_in[4];
    const float* b_out = (const float*)d_in[5];
    float* out = (float*)d_out;

    const size_t xin_bytes  = (size_t)SEQ * BATCH * NH * sizeof(ushort);  // 134 MB
    const size_t flag_bytes = (size_t)NBLK * NCHUNK * sizeof(uint);       // 8 KB

    if (ws_size >= xin_bytes + flag_bytes) {
        uint2* xin  = (uint2*)d_ws;
        uint* flags = (uint*)((char*)d_ws + xin_bytes);
        hipMemsetAsync(flags, 0, flag_bytes, stream);
        // 8 consumers (dispatched first) + 2048 producers; 96 KB dynamic LDS
        // forces 1 block/CU so producers never co-reside with scan CUs.
        elman_fused<<<NBLK + NBLK * NCHUNK, 512, 96 * 1024, stream>>>(
            x, W_in, b_in, W_rec, W_out, b_out, out, xin, flags);
    } else if (ws_size >= xin_bytes) {
        uint2* xin = (uint2*)d_ws;
        dim3 g1(NBLK, SEQ / TCHUNK);
        xin_gemm<<<g1, 256, 0, stream>>>(x, W_in, b_in, xin);
        elman_scan<<<NBLK, 512, 0, stream>>>(xin, W_rec, W_out, b_out, out);
    }
}